// Round 9
// baseline (632.681 us; speedup 1.0000x reference)
//
#include <hip/hip_runtime.h>
#include <hip/hip_bf16.h>
#include <cstdint>

#define L_SEQ 1024
#define BSZ   16
#define DIN   2048
#define DD    2048
#define MROWS (L_SEQ * BSZ)   // 16384
#define NCOLS (3 * DD)        // 6144
#define BKT   64              // K per tile
#define NT    (DIN / BKT)     // 32 K-tiles

typedef __attribute__((ext_vector_type(8)))  short  short8;
typedef __attribute__((ext_vector_type(4)))  float  f32x4;
typedef __attribute__((ext_vector_type(16))) float  f32x16;
typedef __attribute__((ext_vector_type(4)))  ushort ushort4v;

typedef const __attribute__((address_space(1))) void* gas_ptr;
typedef __attribute__((address_space(3))) void*       las_ptr;

#define GLOAD16(g, l) __builtin_amdgcn_global_load_lds((gas_ptr)(g), (las_ptr)(l), 16, 0, 0)

__device__ __forceinline__ float bf2f(ushort u) {
    return __uint_as_float(((uint32_t)u) << 16);
}
__device__ __forceinline__ ushort f2bf(float f) {
    uint32_t u = __float_as_uint(f);
    uint32_t r = u + 0x7FFFu + ((u >> 16) & 1u);  // RNE
    return (ushort)(r >> 16);
}

// ---------------- K0: fused  x f32->bf16  +  W transpose/deinterleave ----------------
__global__ __launch_bounds__(256) void pre_kernel(const f32x4* __restrict__ x4,
                                                  ushort4v* __restrict__ xb4,
                                                  const float* __restrict__ W,
                                                  ushort* __restrict__ WT) {
    __shared__ float tile[64][65];
    int bid = blockIdx.x;
    if (bid < 2048) {
        int i = bid * 256 + threadIdx.x;
        const int n4 = MROWS * DIN / 4;
        const int stride = 2048 * 256;
        for (; i < n4; i += stride) {
            f32x4 v = x4[i];
            ushort4v o;
            o.x = f2bf(v.x); o.y = f2bf(v.y); o.z = f2bf(v.z); o.w = f2bf(v.w);
            xb4[i] = o;
        }
    } else {
        int b2 = bid - 2048;
        int k0 = (b2 & 31) * 64;
        int n0 = (b2 >> 5) * 64;
        int c  = threadIdx.x & 63;
        int r0 = threadIdx.x >> 6;
#pragma unroll
        for (int rr = 0; rr < 16; ++rr) {
            int r = r0 + rr * 4;
            tile[r][c] = W[(size_t)(k0 + r) * NCOLS + n0 + c];
        }
        __syncthreads();
#pragma unroll
        for (int rr = 0; rr < 16; ++rr) {
            int r = r0 + rr * 4;
            int n = n0 + r;
            int nprime = (n % 3) * DD + (n / 3);
            WT[(size_t)nprime * DIN + k0 + c] = f2bf(tile[c][r]);
        }
    }
}

// ---------------- K1: 256x256 GEMM, round-6 skeleton, 32x32x16 MFMA (swapped operands) ----
// Slots per buffer: 0=A0 1=A1 2=B0 3=B1 (16KB each). Stage/vmcnt/barrier schedule is
// byte-identical to the verified round-6 ledger; only the fragment shape changed.
#define SLOT(b, s) (&lds8[(((b) << 2) + (s)) * 8192])

#define STAGE_A(b, h, kt) do {                                                   \
    const ushort* _g = Ab + (size_t)((h) * 64 + idx) * DIN + (kt) * BKT + akc;   \
    ushort* _l = SLOT(b, (h)) + tid * 8;                                         \
    GLOAD16(_g, _l);                                                             \
    GLOAD16(_g + (size_t)128 * DIN, _l + 4096);                                  \
} while (0)

#define STAGE_B(b, h2, kt) do {                                                  \
    const ushort* _g0 = Bb + (size_t)(brow0 + (h2) * 32) * DIN + (kt) * BKT + akc;\
    const ushort* _g1 = Bb + (size_t)(brow1 + (h2) * 32) * DIN + (kt) * BKT + akc;\
    ushort* _l = SLOT(b, 2 + (h2)) + tid * 8;                                    \
    GLOAD16(_g0, _l);                                                            \
    GLOAD16(_g1, _l + 4096);                                                     \
} while (0)

// Full-K fragment loads (preserve slot-release ledger: a slot is reg-captured in one phase).
// A slot h -> dst[8]: [mfin(2)][ks(4)]; rows wm*64 + mfin*32 + (l&31); chunk' = (2ks+h5)^(l31&7).
#define LD_A32(dst, b, h) do { const ushort* _s = SLOT(b, (h)) + a_r0;           \
    _Pragma("unroll") for (int _mf = 0; _mf < 2; ++_mf)                          \
    _Pragma("unroll") for (int _ks = 0; _ks < 4; ++_ks)                          \
        dst[_mf * 4 + _ks] = *(const short8*)(_s + _mf * 2048 + ccs[_ks]);       \
} while (0)

// B slot h2 -> dst[4]: [ks(4)]; rows wn*32 + (l&31).
#define LD_B32(dst, b, h2) do { const ushort* _s = SLOT(b, 2 + (h2)) + b_r0;     \
    _Pragma("unroll") for (int _ks = 0; _ks < 4; ++_ks)                          \
        dst[_ks] = *(const short8*)(_s + ccs[_ks]);                              \
} while (0)

// Swapped operands: D = mfma(b, a, C) -> n = (reg&3)+8*(reg>>2)+4*(l>>5), m = l&31.
#define MM32(mb, bArr, nf, aArr) do {                                            \
    __builtin_amdgcn_s_setprio(1);                                               \
    _Pragma("unroll") for (int _ks = 0; _ks < 4; ++_ks)                          \
    _Pragma("unroll") for (int _mf = 0; _mf < 2; ++_mf)                          \
        acc[(mb) + _mf][nf] = __builtin_amdgcn_mfma_f32_32x32x16_bf16(           \
            bArr[_ks], aArr[_mf * 4 + _ks], acc[(mb) + _mf][nf], 0, 0, 0);       \
    __builtin_amdgcn_s_setprio(0);                                               \
    __builtin_amdgcn_sched_barrier(0);                                           \
} while (0)

#define BARF() do { __builtin_amdgcn_sched_barrier(0);                           \
    __builtin_amdgcn_s_barrier();                                                \
    __builtin_amdgcn_sched_barrier(0); } while (0)

__global__ __launch_bounds__(512, 2) void sru_gemm8(const ushort* __restrict__ A,
                                                    const ushort* __restrict__ Bt,
                                                    const float*  __restrict__ bias,
                                                    ushort* __restrict__ u0,
                                                    ushort* __restrict__ g1,
                                                    ushort* __restrict__ g2) {
    __shared__ alignas(16) ushort lds8[65536];   // 128 KiB

    int bid = blockIdx.x;                        // 1536 blocks (%8==0 -> bijective swizzle)
    int swz = (bid & 7) * 192 + (bid >> 3);
    int bm0 = (swz / 24) * 256;
    int bn0 = (swz % 24) * 256;

    int tid  = threadIdx.x;
    int wave = tid >> 6, lane = tid & 63;
    int wm = wave >> 2, wn = wave & 3;

    // staging constants (inverse-swizzled source)
    int idx    = tid >> 3;
    int schunk = (tid & 7) ^ (idx & 7);
    int akc    = schunk * 8;
    int brow0  = (idx >> 5) * 64 + (idx & 31);
    int brow1  = ((idx >> 5) + 2) * 64 + (idx & 31);
    const ushort* Ab = A  + (size_t)bm0 * DIN;
    const ushort* Bb = Bt + (size_t)bn0 * DIN;

    // fragment-read constants (swizzled ds_read), 32x32x16 layout:
    // lane holds row l&31, k = (l>>5)*8 + j within each K=16 step.
    int l31 = lane & 31, h5 = lane >> 5;
    int ccs[4];
#pragma unroll
    for (int ks = 0; ks < 4; ++ks) ccs[ks] = ((2 * ks + h5) ^ (l31 & 7)) * 8;
    int a_r0 = (wm * 64 + l31) * 64;
    int b_r0 = (wn * 32 + l31) * 64;

    f32x16 acc[4][2];
#pragma unroll
    for (int i = 0; i < 4; ++i)
#pragma unroll
        for (int j = 0; j < 2; ++j)
#pragma unroll
            for (int r = 0; r < 16; ++r) acc[i][j][r] = 0.f;

    // prologue: tile0 fully + tile1's A0,B0; wait tile0 landed (outstanding = 4)
    STAGE_A(0, 0, 0); STAGE_A(0, 1, 0); STAGE_B(0, 0, 0); STAGE_B(0, 1, 0);
    STAGE_A(1, 0, 1); STAGE_B(1, 0, 1);
    asm volatile("s_waitcnt vmcnt(4)" ::: "memory");
    BARF();

    short8 aLo[8], aHi[8], bF0[4], bF1[4];

    for (int t = 0; t < NT; ++t) {
        int cur = t & 1, nxt = cur ^ 1;
        // ph0: capture A0-cur + B0-cur into regs; MM(mf01 x nf0)
        LD_A32(aLo, cur, 0);
        LD_B32(bF0, cur, 0);
        STAGE_A(nxt, 1, t + 1);
        BARF(); MM32(0, bF0, 0, aLo); BARF();
        // ph1: capture B1-cur; MM(mf01 x nf1)
        LD_B32(bF1, cur, 1);
        STAGE_B(nxt, 1, t + 1);
        BARF(); MM32(0, bF1, 1, aLo); BARF();
        // ph2: capture A1-cur; overwrite A0-cur (reg-captured ph0) for t+2
        LD_A32(aHi, cur, 1);
        STAGE_A(cur, 0, t + 2);
        BARF(); MM32(2, bF0, 0, aHi); BARF();
        // ph3: overwrite B0-cur (captured ph0) for t+2; vmcnt(4) proves t+1 landed
        STAGE_B(cur, 0, t + 2);
        asm volatile("s_waitcnt vmcnt(4)" ::: "memory");
        BARF(); MM32(2, bF1, 1, aHi); BARF();
    }
    asm volatile("s_waitcnt vmcnt(0)" ::: "memory");  // drain dead tail stages

    // epilogue (swapped 32x32 layout): acc[mf][nf] reg q ->
    // row = bm0 + wm*128 + mf*32 + (l&31);
    // col = bn0' + wn*64 + nf*32 + (q>>2)*8 + 4*h5 + (q&3)  -> pack 4, one 8B store
    int region = bn0 >> 11;                      // 0:u0 1:g1 2:g2
    int col0 = (bn0 & (DD - 1)) + wn * 64 + 4 * h5;
    int rowm = bm0 + wm * 128 + l31;
    if (region == 0) {
#pragma unroll
        for (int mf = 0; mf < 4; ++mf) {
            size_t rb = (size_t)(rowm + mf * 32) * DD;
#pragma unroll
            for (int nf = 0; nf < 2; ++nf)
#pragma unroll
                for (int qb = 0; qb < 4; ++qb) {
                    uint32_t lo, hi;
                    float v0 = acc[mf][nf][qb * 4 + 0], v1 = acc[mf][nf][qb * 4 + 1];
                    float v2 = acc[mf][nf][qb * 4 + 2], v3 = acc[mf][nf][qb * 4 + 3];
                    asm("v_cvt_pk_bf16_f32 %0, %1, %2" : "=v"(lo) : "v"(v0), "v"(v1));
                    asm("v_cvt_pk_bf16_f32 %0, %1, %2" : "=v"(hi) : "v"(v2), "v"(v3));
                    uint2 pk; pk.x = lo; pk.y = hi;
                    *(uint2*)&u0[rb + col0 + nf * 32 + qb * 8] = pk;
                }
        }
    } else {
        const float* bp = bias + (size_t)(region - 1) * DD;
        ushort* gp = (region == 1) ? g1 : g2;
#pragma unroll
        for (int nf = 0; nf < 2; ++nf)
#pragma unroll
            for (int qb = 0; qb < 4; ++qb) {
                float4 bv = *(const float4*)&bp[col0 + nf * 32 + qb * 8];
#pragma unroll
                for (int mf = 0; mf < 4; ++mf) {
                    float v0 = acc[mf][nf][qb * 4 + 0], v1 = acc[mf][nf][qb * 4 + 1];
                    float v2 = acc[mf][nf][qb * 4 + 2], v3 = acc[mf][nf][qb * 4 + 3];
                    float s0 = 1.f / (1.f + __expf(-(v0 + bv.x)));
                    float s1 = 1.f / (1.f + __expf(-(v1 + bv.y)));
                    float s2 = 1.f / (1.f + __expf(-(v2 + bv.z)));
                    float s3 = 1.f / (1.f + __expf(-(v3 + bv.w)));
                    uint32_t lo, hi;
                    asm("v_cvt_pk_bf16_f32 %0, %1, %2" : "=v"(lo) : "v"(s0), "v"(s1));
                    asm("v_cvt_pk_bf16_f32 %0, %1, %2" : "=v"(hi) : "v"(s2), "v"(s3));
                    uint2 pk; pk.x = lo; pk.y = hi;
                    *(uint2*)&gp[(size_t)(rowm + mf * 32) * DD + col0 + nf * 32 + qb * 8] = pk;
                }
            }
    }
}

// ---------------- K2: sequential recurrence over L, one thread per (b,d) chain ----------------
__global__ __launch_bounds__(64) void sru_rec(const ushort* __restrict__ u0,
                                              const ushort* __restrict__ g1,
                                              const ushort* __restrict__ g2,
                                              const ushort* __restrict__ xb,
                                              const float*  __restrict__ c0,
                                              float* __restrict__ h,
                                              float* __restrict__ c_last) {
    int t = blockIdx.x * 64 + threadIdx.x;   // t = b*DD + d
    float c = c0[t];
#pragma unroll 16
    for (int l = 0; l < L_SEQ; ++l) {
        int ix = l * (BSZ * DD) + t;
        float uu  = bf2f(u0[ix]);
        float gg1 = bf2f(g1[ix]);
        float gg2 = bf2f(g2[ix]);
        float xx  = bf2f(xb[ix]);
        c = (c - uu) * gg1 + uu;
        float e  = __expf(-2.f * fabsf(c));
        float th = (1.f - e) / (1.f + e);
        th = copysignf(th, c);
        h[ix] = (th - xx) * gg2 + xx;
    }
    c_last[t] = c;
}

extern "C" void kernel_launch(void* const* d_in, const int* in_sizes, int n_in,
                              void* d_out, int out_size, void* d_ws, size_t ws_size,
                              hipStream_t stream) {
    const float* x    = (const float*)d_in[0];
    const float* c0   = (const float*)d_in[1];
    const float* W    = (const float*)d_in[2];
    const float* bias = (const float*)d_in[3];
    float* out = (float*)d_out;

    char* ws = (char*)d_ws;
    ushort* xb = (ushort*)(ws);                       //  67,108,864 B  (x bf16)
    ushort* WT = (ushort*)(ws + 67108864);            //  25,165,824 B  (W^T bf16, deinterleaved)
    ushort* u0 = (ushort*)(ws + 92274688);            //  67,108,864 B  (u0 bf16)
    ushort* g1 = (ushort*)(ws + 159383552);           //  67,108,864 B
    ushort* g2 = (ushort*)(ws + 226492416);           //  67,108,864 B  -> 293,601,280 total

    hipLaunchKernelGGL(pre_kernel, dim3(5120), dim3(256), 0, stream,
                       (const f32x4*)x, (ushort4v*)xb, W, WT);
    hipLaunchKernelGGL(sru_gemm8, dim3(1536), dim3(512), 0, stream, xb, WT, bias, u0, g1, g2);
    hipLaunchKernelGGL(sru_rec, dim3(512), dim3(64), 0, stream,
                       u0, g1, g2, xb, c0, out, out + (size_t)MROWS * DD);
}

// Round 10
// 614.010 us; speedup vs baseline: 1.0304x; 1.0304x over previous
//
#include <hip/hip_runtime.h>
#include <hip/hip_bf16.h>
#include <cstdint>

#define L_SEQ 1024
#define BSZ   16
#define DIN   2048
#define DD    2048
#define MROWS (L_SEQ * BSZ)   // 16384
#define NCOLS (3 * DD)        // 6144
#define BKT   64              // K per tile
#define NT    (DIN / BKT)     // 32 K-tiles

typedef __attribute__((ext_vector_type(8)))  short  short8;
typedef __attribute__((ext_vector_type(4)))  float  f32x4;
typedef __attribute__((ext_vector_type(16))) float  f32x16;
typedef __attribute__((ext_vector_type(4)))  ushort ushort4v;

typedef const __attribute__((address_space(1))) void* gas_ptr;
typedef __attribute__((address_space(3))) void*       las_ptr;

#define GLOAD16(g, l) __builtin_amdgcn_global_load_lds((gas_ptr)(g), (las_ptr)(l), 16, 0, 0)

__device__ __forceinline__ float bf2f(ushort u) {
    return __uint_as_float(((uint32_t)u) << 16);
}
__device__ __forceinline__ ushort f2bf(float f) {
    uint32_t u = __float_as_uint(f);
    uint32_t r = u + 0x7FFFu + ((u >> 16) & 1u);  // RNE
    return (ushort)(r >> 16);
}

// ---------------- K0: fused  x f32->bf16  +  W transpose/deinterleave ----------------
__global__ __launch_bounds__(256) void pre_kernel(const f32x4* __restrict__ x4,
                                                  ushort4v* __restrict__ xb4,
                                                  const float* __restrict__ W,
                                                  ushort* __restrict__ WT) {
    __shared__ float tile[64][65];
    int bid = blockIdx.x;
    if (bid < 2048) {
        int i = bid * 256 + threadIdx.x;
        const int n4 = MROWS * DIN / 4;
        const int stride = 2048 * 256;
        for (; i < n4; i += stride) {
            f32x4 v = x4[i];
            ushort4v o;
            o.x = f2bf(v.x); o.y = f2bf(v.y); o.z = f2bf(v.z); o.w = f2bf(v.w);
            xb4[i] = o;
        }
    } else {
        int b2 = bid - 2048;
        int k0 = (b2 & 31) * 64;
        int n0 = (b2 >> 5) * 64;
        int c  = threadIdx.x & 63;
        int r0 = threadIdx.x >> 6;
#pragma unroll
        for (int rr = 0; rr < 16; ++rr) {
            int r = r0 + rr * 4;
            tile[r][c] = W[(size_t)(k0 + r) * NCOLS + n0 + c];
        }
        __syncthreads();
#pragma unroll
        for (int rr = 0; rr < 16; ++rr) {
            int r = r0 + rr * 4;
            int n = n0 + r;
            int nprime = (n % 3) * DD + (n / 3);
            WT[(size_t)nprime * DIN + k0 + c] = f2bf(tile[c][r]);
        }
    }
}

// ---------------- K1: 256x256 GEMM, round-6 skeleton, 32x32x16 MFMA, FIXED swizzle ----
// Swizzle key(row) = (row&7) ^ ((row>>3)&3): stride-8 rows land on distinct 16B slots,
// removing the round-9 4-way service-group conflict. Same involution applied on staging
// source and ds_read (rule: both-sides-or-neither).
#define SLOT(b, s) (&lds8[(((b) << 2) + (s)) * 8192])

#define STAGE_A(b, h, kt) do {                                                   \
    const ushort* _g = Ab + (size_t)((h) * 64 + idx) * DIN + (kt) * BKT + akc;   \
    ushort* _l = SLOT(b, (h)) + tid * 8;                                         \
    GLOAD16(_g, _l);                                                             \
    GLOAD16(_g + (size_t)128 * DIN, _l + 4096);                                  \
} while (0)

#define STAGE_B(b, h2, kt) do {                                                  \
    const ushort* _g0 = Bb + (size_t)(brow0 + (h2) * 32) * DIN + (kt) * BKT + akc;\
    const ushort* _g1 = Bb + (size_t)(brow1 + (h2) * 32) * DIN + (kt) * BKT + akc;\
    ushort* _l = SLOT(b, 2 + (h2)) + tid * 8;                                    \
    GLOAD16(_g0, _l);                                                            \
    GLOAD16(_g1, _l + 4096);                                                     \
} while (0)

// Full-K fragment loads. A slot h -> dst[8]: [mfin(2)][ks(4)]; B slot h2 -> dst[4].
#define LD_A32(dst, b, h) do { const ushort* _s = SLOT(b, (h)) + a_r0;           \
    _Pragma("unroll") for (int _mf = 0; _mf < 2; ++_mf)                          \
    _Pragma("unroll") for (int _ks = 0; _ks < 4; ++_ks)                          \
        dst[_mf * 4 + _ks] = *(const short8*)(_s + _mf * 2048 + ccs[_ks]);       \
} while (0)

#define LD_B32(dst, b, h2) do { const ushort* _s = SLOT(b, 2 + (h2)) + b_r0;     \
    _Pragma("unroll") for (int _ks = 0; _ks < 4; ++_ks)                          \
        dst[_ks] = *(const short8*)(_s + ccs[_ks]);                              \
} while (0)

// Swapped operands: D = mfma(b, a, C) -> n = (reg&3)+8*(reg>>2)+4*(l>>5), m = l&31.
#define MM32(mb, bArr, nf, aArr) do {                                            \
    __builtin_amdgcn_s_setprio(1);                                               \
    _Pragma("unroll") for (int _ks = 0; _ks < 4; ++_ks)                          \
    _Pragma("unroll") for (int _mf = 0; _mf < 2; ++_mf)                          \
        acc[(mb) + _mf][nf] = __builtin_amdgcn_mfma_f32_32x32x16_bf16(           \
            bArr[_ks], aArr[_mf * 4 + _ks], acc[(mb) + _mf][nf], 0, 0, 0);       \
    __builtin_amdgcn_s_setprio(0);                                               \
    __builtin_amdgcn_sched_barrier(0);                                           \
} while (0)

#define BARF() do { __builtin_amdgcn_sched_barrier(0);                           \
    __builtin_amdgcn_s_barrier();                                                \
    __builtin_amdgcn_sched_barrier(0); } while (0)

__global__ __launch_bounds__(512, 2) void sru_gemm8(const ushort* __restrict__ A,
                                                    const ushort* __restrict__ Bt,
                                                    const float*  __restrict__ bias,
                                                    ushort* __restrict__ u0,
                                                    ushort* __restrict__ g1,
                                                    ushort* __restrict__ g2) {
    __shared__ alignas(16) ushort lds8[65536];   // 128 KiB

    int bid = blockIdx.x;                        // 1536 blocks (%8==0 -> bijective swizzle)
    int swz = (bid & 7) * 192 + (bid >> 3);
    int bm0 = (swz / 24) * 256;
    int bn0 = (swz % 24) * 256;

    int tid  = threadIdx.x;
    int wave = tid >> 6, lane = tid & 63;
    int wm = wave >> 2, wn = wave & 3;

    // staging constants (inverse-swizzled source, NEW key = (idx&7)^((idx>>3)&3))
    int idx    = tid >> 3;
    int schunk = (tid & 7) ^ (idx & 7) ^ ((idx >> 3) & 3);
    int akc    = schunk * 8;
    int brow0  = (idx >> 5) * 64 + (idx & 31);
    int brow1  = ((idx >> 5) + 2) * 64 + (idx & 31);
    const ushort* Ab = A  + (size_t)bm0 * DIN;
    const ushort* Bb = Bt + (size_t)bn0 * DIN;

    // fragment-read constants: lane holds row l&31, k = (l>>5)*8 + j per K=16 step.
    // Read key reduces to (l31&7)^((l31>>3)&3) for all wm/mf/wn/h2 (offsets ≡0 mod 4/8).
    int l31 = lane & 31, h5 = lane >> 5;
    int key = (l31 & 7) ^ ((l31 >> 3) & 3);
    int ccs[4];
#pragma unroll
    for (int ks = 0; ks < 4; ++ks) ccs[ks] = ((2 * ks + h5) ^ key) * 8;
    int a_r0 = (wm * 64 + l31) * 64;
    int b_r0 = (wn * 32 + l31) * 64;

    f32x16 acc[4][2];
#pragma unroll
    for (int i = 0; i < 4; ++i)
#pragma unroll
        for (int j = 0; j < 2; ++j)
#pragma unroll
            for (int r = 0; r < 16; ++r) acc[i][j][r] = 0.f;

    // prologue: tile0 fully + tile1's A0,B0; wait tile0 landed (outstanding = 4)
    STAGE_A(0, 0, 0); STAGE_A(0, 1, 0); STAGE_B(0, 0, 0); STAGE_B(0, 1, 0);
    STAGE_A(1, 0, 1); STAGE_B(1, 0, 1);
    asm volatile("s_waitcnt vmcnt(4)" ::: "memory");
    BARF();

    short8 aLo[8], aHi[8], bF0[4], bF1[4];

    for (int t = 0; t < NT; ++t) {
        int cur = t & 1, nxt = cur ^ 1;
        // ph0: capture A0-cur + B0-cur into regs; MM(mf01 x nf0)
        LD_A32(aLo, cur, 0);
        LD_B32(bF0, cur, 0);
        STAGE_A(nxt, 1, t + 1);
        BARF(); MM32(0, bF0, 0, aLo); BARF();
        // ph1: capture B1-cur; MM(mf01 x nf1)
        LD_B32(bF1, cur, 1);
        STAGE_B(nxt, 1, t + 1);
        BARF(); MM32(0, bF1, 1, aLo); BARF();
        // ph2: capture A1-cur; overwrite A0-cur (reg-captured ph0) for t+2
        LD_A32(aHi, cur, 1);
        STAGE_A(cur, 0, t + 2);
        BARF(); MM32(2, bF0, 0, aHi); BARF();
        // ph3: overwrite B0-cur (captured ph0) for t+2; vmcnt(4) proves t+1 landed
        STAGE_B(cur, 0, t + 2);
        asm volatile("s_waitcnt vmcnt(4)" ::: "memory");
        BARF(); MM32(2, bF1, 1, aHi); BARF();
    }
    asm volatile("s_waitcnt vmcnt(0)" ::: "memory");  // drain dead tail stages

    // epilogue (swapped 32x32 layout): acc[mf][nf] reg q ->
    // row = bm0 + wm*128 + mf*32 + (l&31);
    // col = bn0' + wn*64 + nf*32 + (q>>2)*8 + 4*h5 + (q&3)  -> pack 4, one 8B store
    int region = bn0 >> 11;                      // 0:u0 1:g1 2:g2
    int col0 = (bn0 & (DD - 1)) + wn * 64 + 4 * h5;
    int rowm = bm0 + wm * 128 + l31;
    if (region == 0) {
#pragma unroll
        for (int mf = 0; mf < 4; ++mf) {
            size_t rb = (size_t)(rowm + mf * 32) * DD;
#pragma unroll
            for (int nf = 0; nf < 2; ++nf)
#pragma unroll
                for (int qb = 0; qb < 4; ++qb) {
                    uint32_t lo, hi;
                    float v0 = acc[mf][nf][qb * 4 + 0], v1 = acc[mf][nf][qb * 4 + 1];
                    float v2 = acc[mf][nf][qb * 4 + 2], v3 = acc[mf][nf][qb * 4 + 3];
                    asm("v_cvt_pk_bf16_f32 %0, %1, %2" : "=v"(lo) : "v"(v0), "v"(v1));
                    asm("v_cvt_pk_bf16_f32 %0, %1, %2" : "=v"(hi) : "v"(v2), "v"(v3));
                    uint2 pk; pk.x = lo; pk.y = hi;
                    *(uint2*)&u0[rb + col0 + nf * 32 + qb * 8] = pk;
                }
        }
    } else {
        const float* bp = bias + (size_t)(region - 1) * DD;
        ushort* gp = (region == 1) ? g1 : g2;
#pragma unroll
        for (int nf = 0; nf < 2; ++nf)
#pragma unroll
            for (int qb = 0; qb < 4; ++qb) {
                float4 bv = *(const float4*)&bp[col0 + nf * 32 + qb * 8];
#pragma unroll
                for (int mf = 0; mf < 4; ++mf) {
                    float v0 = acc[mf][nf][qb * 4 + 0], v1 = acc[mf][nf][qb * 4 + 1];
                    float v2 = acc[mf][nf][qb * 4 + 2], v3 = acc[mf][nf][qb * 4 + 3];
                    float s0 = 1.f / (1.f + __expf(-(v0 + bv.x)));
                    float s1 = 1.f / (1.f + __expf(-(v1 + bv.y)));
                    float s2 = 1.f / (1.f + __expf(-(v2 + bv.z)));
                    float s3 = 1.f / (1.f + __expf(-(v3 + bv.w)));
                    uint32_t lo, hi;
                    asm("v_cvt_pk_bf16_f32 %0, %1, %2" : "=v"(lo) : "v"(s0), "v"(s1));
                    asm("v_cvt_pk_bf16_f32 %0, %1, %2" : "=v"(hi) : "v"(s2), "v"(s3));
                    uint2 pk; pk.x = lo; pk.y = hi;
                    *(uint2*)&gp[(size_t)(rowm + mf * 32) * DD + col0 + nf * 32 + qb * 8] = pk;
                }
            }
    }
}

// ---------------- K2: sequential recurrence over L, one thread per (b,d) chain ----------------
__global__ __launch_bounds__(64) void sru_rec(const ushort* __restrict__ u0,
                                              const ushort* __restrict__ g1,
                                              const ushort* __restrict__ g2,
                                              const ushort* __restrict__ xb,
                                              const float*  __restrict__ c0,
                                              float* __restrict__ h,
                                              float* __restrict__ c_last) {
    int t = blockIdx.x * 64 + threadIdx.x;   // t = b*DD + d
    float c = c0[t];
#pragma unroll 16
    for (int l = 0; l < L_SEQ; ++l) {
        int ix = l * (BSZ * DD) + t;
        float uu  = bf2f(u0[ix]);
        float gg1 = bf2f(g1[ix]);
        float gg2 = bf2f(g2[ix]);
        float xx  = bf2f(xb[ix]);
        c = (c - uu) * gg1 + uu;
        float e  = __expf(-2.f * fabsf(c));
        float th = (1.f - e) / (1.f + e);
        th = copysignf(th, c);
        h[ix] = (th - xx) * gg2 + xx;
    }
    c_last[t] = c;
}

extern "C" void kernel_launch(void* const* d_in, const int* in_sizes, int n_in,
                              void* d_out, int out_size, void* d_ws, size_t ws_size,
                              hipStream_t stream) {
    const float* x    = (const float*)d_in[0];
    const float* c0   = (const float*)d_in[1];
    const float* W    = (const float*)d_in[2];
    const float* bias = (const float*)d_in[3];
    float* out = (float*)d_out;

    char* ws = (char*)d_ws;
    ushort* xb = (ushort*)(ws);                       //  67,108,864 B  (x bf16)
    ushort* WT = (ushort*)(ws + 67108864);            //  25,165,824 B  (W^T bf16, deinterleaved)
    ushort* u0 = (ushort*)(ws + 92274688);            //  67,108,864 B  (u0 bf16)
    ushort* g1 = (ushort*)(ws + 159383552);           //  67,108,864 B
    ushort* g2 = (ushort*)(ws + 226492416);           //  67,108,864 B  -> 293,601,280 total

    hipLaunchKernelGGL(pre_kernel, dim3(5120), dim3(256), 0, stream,
                       (const f32x4*)x, (ushort4v*)xb, W, WT);
    hipLaunchKernelGGL(sru_gemm8, dim3(1536), dim3(512), 0, stream, xb, WT, bias, u0, g1, g2);
    hipLaunchKernelGGL(sru_rec, dim3(512), dim3(64), 0, stream,
                       u0, g1, g2, xb, c0, out, out + (size_t)MROWS * DD);
}